// Round 14
// baseline (1432.303 us; speedup 1.0000x reference)
//
#include <hip/hip_runtime.h>
#include <math.h>

typedef unsigned short u16;
typedef __attribute__((ext_vector_type(4))) unsigned short u16x4;
typedef __attribute__((ext_vector_type(8))) unsigned short u16x8;
typedef __attribute__((ext_vector_type(8))) short short8;   // MFMA A/B frag (8 bf16)
typedef __attribute__((ext_vector_type(4))) float f32x4;    // MFMA C/D frag

#define BB 8
#define CC 256
#define LL 77
#define HW 16384    // 128*128
#define XROW 520    // XT row stride in ch (513 padded to 8-multiple)

__device__ __forceinline__ float bf2f(u16 h) {
  return __uint_as_float(((unsigned)h) << 16);
}
__device__ __forceinline__ u16 f2bf(float f) {   // round-to-nearest-even
  unsigned u = __float_as_uint(f);
  unsigned r = (u + 0x7fffu + ((u >> 16) & 1u)) >> 16;
  return (u16)r;
}

// ---------------- workspace layout (BYTE offsets) ----------------
static const size_t OFF_XT    = 0;
static const size_t OFF_B     = 136314880;
static const size_t OFF_GVECB = 630784;          // relative to OFF_B
static const size_t OFF_PG    = 137363456;       // P [8][16384][96] bf16 (25.2MB)
static const size_t OFF_GNSUM = 203423744;
static const size_t WS_BYTES_NEEDED = 203425792;  // ~194.0 MiB
// Region-A reuse offsets (absolute):
static const size_t OFF_Y2T = 0;
static const size_t OFF_GA  = 16777216;
static const size_t OFF_GB  = 16785408;
static const size_t OFF_Y3  = 16793600;
// d_out scratch: wt1, wt2, wtc2 (dead until final upsample)
static const size_t WT1_BYTES = 9u * 256u * 544u * 2u;   // 2,506,752
static const size_t WT2_BYTES = 9u * 64u * 256u * 2u;    // 294,912

// ---------------- diagnostic fill (only if ws too small) ----------------
__global__ __launch_bounds__(256) void fill_kernel(float* __restrict__ out,
                                                   int n, float v) {
  int i = blockIdx.x * 256 + threadIdx.x;
  if (i < n) out[i] = v;
}

__global__ __launch_bounds__(512) void zero_gnsum(float* __restrict__ g) {
  g[threadIdx.x] = 0.f;
}

// ---------------- weight transpose: w[oc][ic][3][3] f32 -> wt[kk][oc][icpad] bf16
__global__ __launch_bounds__(256) void prep_wt(
    const float* __restrict__ w, u16* __restrict__ wt,
    int OC, int ICSRC, int ICPAD, int total) {
  int idx = blockIdx.x * 256 + threadIdx.x;
  if (idx >= total) return;
  int ic = idx % ICPAD;
  int oc = (idx / ICPAD) % OC;
  int kk = idx / (ICPAD * OC);
  float v = 0.f;
  if (ic < ICSRC) v = w[((size_t)oc * ICSRC + ic) * 9 + kk];
  wt[idx] = f2bf(v);
}

// ---------------- pos -> XT img channels directly (all 8 batches) ----------
__global__ __launch_bounds__(256) void pos_xt(
    const float* __restrict__ sp1_w, const float* __restrict__ sp1_b,
    const float* __restrict__ sp2_w, const float* __restrict__ sp2_b,
    u16* __restrict__ xt) {
  __shared__ float hid[64 * 64];   // [pxl][h] 16 KB
  __shared__ u16 pv[64 * 256];     // [pxl][c] 32 KB
  const int tid = threadIdx.x;
  const int px0 = blockIdx.x * 64;
  #pragma unroll
  for (int i = 0; i < 16; ++i) {
    int slot = i * 256 + tid;
    int pxl = slot >> 6, h = slot & 63;
    int px = px0 + pxl;
    float xx = -1.f + (px & 127) * (2.f / 127.f);
    float yy = -1.f + (px >> 7) * (2.f / 127.f);
    hid[slot] = fmaxf(sp1_w[2 * h] * xx + sp1_w[2 * h + 1] * yy + sp1_b[h], 0.f);
  }
  float wr[64];
  #pragma unroll
  for (int q = 0; q < 16; ++q) {
    float4 v = *reinterpret_cast<const float4*>(sp2_w + tid * 64 + q * 4);
    wr[q * 4] = v.x; wr[q * 4 + 1] = v.y; wr[q * 4 + 2] = v.z; wr[q * 4 + 3] = v.w;
  }
  const float sb = sp2_b[tid];
  __syncthreads();
  for (int pxl = 0; pxl < 64; ++pxl) {
    float acc = sb;
    const float* hr = &hid[pxl * 64];
    #pragma unroll
    for (int h = 0; h < 64; ++h) acc = fmaf(wr[h], hr[h], acc);
    pv[pxl * 256 + tid] = f2bf(acc);
  }
  __syncthreads();
  for (int b = 0; b < BB; ++b) {
    u16* xb = xt + ((size_t)b * HW + px0) * XROW;
    #pragma unroll
    for (int it = 0; it < 8; ++it) {
      int slot = it * 256 + tid;
      int pxl = slot >> 5, cg = slot & 31;
      *reinterpret_cast<u16x8*>(xb + (size_t)pxl * XROW + cg * 8) =
          *reinterpret_cast<const u16x8*>(&pv[pxl * 256 + cg * 8]);
    }
  }
}

// ---------------- conv1: 3->64, stride 2, relu; writes x1T [px][64] ---------
__global__ __launch_bounds__(256) void conv1_kernel(
    const float* __restrict__ in, const float* __restrict__ w,
    const float* __restrict__ bias, u16* __restrict__ x1t) {
  __shared__ float wl[27 * 64];   // [t][oc]
  __shared__ float bl[64];
  const int tid = threadIdx.x;
  const int oh = blockIdx.x;
  const int b = blockIdx.y;
  for (int i = tid; i < 27 * 64; i += 256) {
    int oc = i & 63;
    int t = i >> 6;
    wl[t * 64 + oc] = w[oc * 27 + t];
  }
  if (tid < 64) bl[tid] = bias[tid];
  __syncthreads();
  const int ow = tid;
  float acc[64];
  #pragma unroll
  for (int oc = 0; oc < 64; ++oc) acc[oc] = bl[oc];
  for (int ic = 0; ic < 3; ++ic) {
    #pragma unroll
    for (int kh = 0; kh < 3; ++kh) {
      int ih = 2 * oh + kh - 1;
      if ((unsigned)ih >= 512u) continue;
      const float* row = in + ((size_t)(b * 3 + ic) * 512 + ih) * 512;
      int iw = 2 * ow - 1;
      float v0 = (iw >= 0) ? row[iw] : 0.f;
      float v1 = row[iw + 1];
      float v2 = row[iw + 2];
      const float* wr = &wl[(ic * 3 + kh) * 192];
      #pragma unroll
      for (int oc = 0; oc < 64; ++oc)
        acc[oc] += v0 * wr[oc] + v1 * wr[64 + oc] + v2 * wr[128 + oc];
    }
  }
  u16* orow = x1t + ((size_t)b * 65536 + oh * 256 + ow) * 64;
  #pragma unroll
  for (int q = 0; q < 8; ++q) {
    u16x8 o;
    #pragma unroll
    for (int k = 0; k < 8; ++k) o[k] = f2bf(fmaxf(acc[q * 8 + k], 0.f));
    *reinterpret_cast<u16x8*>(orow + q * 8) = o;
  }
}

// ---------------- conv2 MFMA: 64->256, stride 2; XT[p][oc] += relu(conv) ----
__global__ __launch_bounds__(256) void conv2_mfma(
    const u16* __restrict__ x1t, const u16* __restrict__ wt,
    const float* __restrict__ bias, u16* __restrict__ xt) {
  __shared__ u16 lb[15480];   // 1935 slots * 8 u16 = 30,960 B
  const int tid = threadIdx.x;
  const int lane = tid & 63;
  const int w = tid >> 6;
  const int oh = blockIdx.x >> 1;
  const int half = blockIdx.x & 1;
  const int ow0 = half << 6;
  const int b = blockIdx.z;
  const int colA = lane & 15;
  const int g = lane >> 4;
  const int oc0w = w * 64;

  f32x4 acc[4][4];
  #pragma unroll
  for (int of = 0; of < 4; ++of) {
    f32x4 bv;
    #pragma unroll
    for (int r = 0; r < 4; ++r) bv[r] = bias[oc0w + of * 16 + g * 4 + r];
    #pragma unroll
    for (int pf = 0; pf < 4; ++pf) acc[of][pf] = bv;
  }

  const u16* xb = x1t + (size_t)b * 65536 * 64;
  for (int ch = 0; ch < 2; ++ch) {
    __syncthreads();
    for (int slot = tid; slot < 1548; slot += 256) {
      int icg = slot & 3;
      int rc = slot >> 2;
      int kh, ip;
      if (rc < 192) {
        kh = rc / 64; int i = rc - kh * 64; ip = (ow0 << 1) + 2 * i;
      } else {
        int rc2 = rc - 192; kh = rc2 / 65; int j = rc2 - kh * 65;
        ip = (ow0 << 1) - 1 + 2 * j;
      }
      int ih = 2 * oh + kh - 1;
      u16x8 v = {0, 0, 0, 0, 0, 0, 0, 0};
      if ((unsigned)ih < 256u && (unsigned)ip < 256u)
        v = *reinterpret_cast<const u16x8*>(
            xb + ((size_t)(ih * 256 + ip)) * 64 + ch * 32 + icg * 8);
      *reinterpret_cast<u16x8*>(&lb[(rc * 5 + icg) << 3]) = v;
    }
    __syncthreads();
    #pragma unroll
    for (int kk = 0; kk < 9; ++kk) {
      const int kh = kk / 3, kw = kk - kh * 3;
      short8 afrag[4];
      const u16* wb = wt + ((size_t)kk * 256 + oc0w + colA) * 64 + ch * 32 + g * 8;
      #pragma unroll
      for (int of = 0; of < 4; ++of)
        afrag[of] = *reinterpret_cast<const short8*>(wb + (size_t)of * 16 * 64);
      #pragma unroll
      for (int pf = 0; pf < 4; ++pf) {
        int ow = pf * 16 + colA;
        int rc = (kw == 1) ? (kh * 64 + ow) : (192 + kh * 65 + ow + (kw >> 1));
        short8 bfrag = *reinterpret_cast<const short8*>(&lb[(rc * 5 + g) << 3]);
        #pragma unroll
        for (int of = 0; of < 4; ++of)
          acc[of][pf] = __builtin_amdgcn_mfma_f32_16x16x32_bf16(
              afrag[of], bfrag, acc[of][pf], 0, 0, 0);
      }
    }
  }
  #pragma unroll
  for (int of = 0; of < 4; ++of) {
    #pragma unroll
    for (int pf = 0; pf < 4; ++pf) {
      int px = oh * 128 + ow0 + pf * 16 + colA;
      int oc = oc0w + of * 16 + g * 4;
      u16* dst = xt + ((size_t)b * HW + px) * XROW + oc;
      u16x4 pz = *reinterpret_cast<const u16x4*>(dst);
      u16x4 o;
      #pragma unroll
      for (int r = 0; r < 4; ++r)
        o[r] = f2bf(fmaxf(acc[of][pf][r], 0.f) + bf2f(pz[r]));
      *reinterpret_cast<u16x4*>(dst) = o;
    }
  }
}

// ---------------- token pipeline: proj -> gate -> l2norm (f32 out) ----------
__global__ __launch_bounds__(256) void token_kernel(
    const float* __restrict__ tok512, const float* __restrict__ proj_w,
    const float* __restrict__ proj_b, const float* __restrict__ gate_w,
    const float* __restrict__ gate_b, float* __restrict__ tok_out) {
  __shared__ float t512[512];
  __shared__ float prj[256];
  __shared__ float red[4];
  int bl = blockIdx.x;
  int c = threadIdx.x;
  const float* trow = tok512 + (size_t)bl * 512;
  t512[c] = trow[c];
  t512[c + 256] = trow[c + 256];
  __syncthreads();
  float acc = proj_b[c];
  #pragma unroll 4
  for (int k = 0; k < 512; ++k) acc = fmaf(t512[k], proj_w[k * 256 + c], acc);
  prj[c] = acc;
  __syncthreads();
  float acc2 = gate_b[c];
  #pragma unroll 4
  for (int k = 0; k < 256; ++k) acc2 = fmaf(prj[k], gate_w[k * 256 + c], acc2);
  float g = 1.f / (1.f + __expf(-acc2));
  float tv = g * acc;
  float ss = tv * tv;
  #pragma unroll
  for (int off = 1; off < 64; off <<= 1) ss += __shfl_xor(ss, off);
  if ((c & 63) == 0) red[c >> 6] = ss;
  __syncthreads();
  float tot = red[0] + red[1] + red[2] + red[3];
  tok_out[(size_t)bl * 256 + c] = tv * (1.f / fmaxf(sqrtf(tot), 1e-12f));
}

// ---------------- gvec ----------------
__global__ __launch_bounds__(256) void gvec_kernel(
    const float* __restrict__ tok, const int* __restrict__ tokens,
    float* __restrict__ gvec) {
  __shared__ float red[4];
  int b = blockIdx.x, c = threadIdx.x;
  float s = 0.f;
  for (int l = 0; l < LL; ++l) {
    if (tokens[b * LL + l] != 0) s += tok[((size_t)b * LL + l) * 256 + c];
  }
  float ss = s * s;
  #pragma unroll
  for (int off = 1; off < 64; off <<= 1) ss += __shfl_xor(ss, off);
  if ((c & 63) == 0) red[c >> 6] = ss;
  __syncthreads();
  float tot = red[0] + red[1] + red[2] + red[3];
  gvec[b * 256 + c] = s * (1.f / fmaxf(sqrtf(tot), 1e-12f));
}

// ---------------- attn pass 1: scores + softmax -> P (global), sim -> XT ----
__global__ __launch_bounds__(256, 1) void attn_score(
    u16* __restrict__ xt, const float* __restrict__ tok,
    const int* __restrict__ tokens, const float* __restrict__ gvec,
    u16* __restrict__ pg) {
  __shared__ u16 ltok[LL * 256];   // bf16 tokens (39.4 KB)
  __shared__ u16 pl[64 * 104];     // P staging [px][l] (13.3 KB)
  __shared__ float lgv[256];
  __shared__ u16 lval[LL + 3];
  const int tid = threadIdx.x;
  const int b = blockIdx.y;
  const int px0 = blockIdx.x * 64;
  for (int slot = tid; slot < LL * 32; slot += 256) {
    int l = slot >> 5, cg = slot & 31;
    const float* tp = tok + ((size_t)b * LL + l) * 256 + cg * 8;
    float4 t0 = *reinterpret_cast<const float4*>(tp);
    float4 t1 = *reinterpret_cast<const float4*>(tp + 4);
    u16x8 v = {f2bf(t0.x), f2bf(t0.y), f2bf(t0.z), f2bf(t0.w),
               f2bf(t1.x), f2bf(t1.y), f2bf(t1.z), f2bf(t1.w)};
    *reinterpret_cast<u16x8*>(&ltok[l * 256 + cg * 8]) = v;
  }
  for (int slot = tid; slot < 64 * 19; slot += 256) {
    int row = slot / 19, lp = LL + slot % 19;
    pl[row * 104 + lp] = 0;
  }
  if (tid < LL) lval[tid] = (tokens[b * LL + tid] != 0) ? 1 : 0;
  lgv[tid] = gvec[b * 256 + tid];
  __syncthreads();
  const int pxl = tid >> 2;
  const int q = tid & 3;
  const int p = px0 + pxl;
  const u16* xr = xt + ((size_t)b * HW + p) * XROW;
  float s[20];
  #pragma unroll
  for (int i = 0; i < 20; ++i) s[i] = 0.f;
  float ssum = 0.f, simacc = 0.f;
  #pragma unroll 1
  for (int c0 = 0; c0 < 256; c0 += 32) {
    float x[32];
    #pragma unroll
    for (int qq = 0; qq < 4; ++qq) {
      u16x8 iv = *reinterpret_cast<const u16x8*>(xr + c0 + qq * 8);
      #pragma unroll
      for (int k = 0; k < 8; ++k) x[qq * 8 + k] = bf2f(iv[k]);
    }
    #pragma unroll
    for (int k = 0; k < 32; ++k) {
      ssum = fmaf(x[k], x[k], ssum);
      simacc = fmaf(x[k], lgv[c0 + k], simacc);
    }
    #pragma unroll
    for (int li = 0; li < 20; ++li) {
      int l = li * 4 + q;
      if (l < LL) {
        const u16* tr = &ltok[l * 256 + c0];
        float a2 = s[li];
        #pragma unroll
        for (int qq = 0; qq < 4; ++qq) {
          u16x8 tv = *reinterpret_cast<const u16x8*>(tr + qq * 8);
          #pragma unroll
          for (int k = 0; k < 8; ++k) a2 = fmaf(x[qq * 8 + k], bf2f(tv[k]), a2);
        }
        s[li] = a2;
      }
    }
  }
  const float invn = 1.f / fmaxf(sqrtf(ssum), 1e-12f);
  const float sc = invn * 0.0625f;
  float m = -1e30f;
  #pragma unroll
  for (int li = 0; li < 20; ++li) {
    int l = li * 4 + q;
    float v = (l < LL) ? (lval[l] ? s[li] * sc : -10000.f) : -1e30f;
    s[li] = v;
    m = fmaxf(m, v);
  }
  m = fmaxf(m, __shfl_xor(m, 1));
  m = fmaxf(m, __shfl_xor(m, 2));
  float sum = 0.f;
  #pragma unroll
  for (int li = 0; li < 20; ++li) {
    float e = __expf(s[li] - m);
    s[li] = e;
    sum += e;
  }
  sum += __shfl_xor(sum, 1);
  sum += __shfl_xor(sum, 2);
  const float rs = 1.f / sum;
  #pragma unroll
  for (int li = 0; li < 20; ++li) {
    int l = li * 4 + q;
    if (l < LL) pl[pxl * 104 + l] = f2bf(s[li] * rs);
  }
  if (q == 0) {
    u16x8 sv = {f2bf(simacc * invn), 0, 0, 0, 0, 0, 0, 0};
    *reinterpret_cast<u16x8*>(xt + ((size_t)b * HW + p) * XROW + 512) = sv;
  }
  __syncthreads();
  u16* pgb = pg + ((size_t)b * HW + px0) * 96;
  #pragma unroll
  for (int it = 0; it < 3; ++it) {
    int slot = it * 256 + tid;
    int row = slot / 12, qq = slot % 12;
    *reinterpret_cast<u16x8*>(pgb + row * 96 + qq * 8) =
        *reinterpret_cast<const u16x8*>(&pl[row * 104 + qq * 8]);
  }
}

// ---------------- attn pass 2: ctx = P @ tok -> XT ctx channels ----------
__global__ __launch_bounds__(256, 1) void attn_ctx(
    u16* __restrict__ xt, const float* __restrict__ tok,
    const u16* __restrict__ pg) {
  __shared__ u16 ltok[LL * 256];
  const int tid = threadIdx.x;
  const int b = blockIdx.y;
  for (int slot = tid; slot < LL * 32; slot += 256) {
    int l = slot >> 5, cg = slot & 31;
    const float* tp = tok + ((size_t)b * LL + l) * 256 + cg * 8;
    float4 t0 = *reinterpret_cast<const float4*>(tp);
    float4 t1 = *reinterpret_cast<const float4*>(tp + 4);
    u16x8 v = {f2bf(t0.x), f2bf(t0.y), f2bf(t0.z), f2bf(t0.w),
               f2bf(t1.x), f2bf(t1.y), f2bf(t1.z), f2bf(t1.w)};
    *reinterpret_cast<u16x8*>(&ltok[l * 256 + cg * 8]) = v;
  }
  __syncthreads();
  const int p = blockIdx.x * 256 + tid;
  const u16* pr = pg + ((size_t)b * HW + p) * 96;
  u16x8 pw[10];
  #pragma unroll
  for (int q = 0; q < 10; ++q)
    pw[q] = *reinterpret_cast<const u16x8*>(pr + q * 8);
  u16* xw = xt + ((size_t)b * HW + p) * XROW + 256;
  #pragma unroll 1
  for (int c0 = 0; c0 < 256; c0 += 32) {
    float a[32];
    #pragma unroll
    for (int k = 0; k < 32; ++k) a[k] = 0.f;
    #pragma unroll
    for (int l = 0; l < LL; ++l) {
      float sl = bf2f(pw[l >> 3][l & 7]);
      const u16* tr = &ltok[l * 256 + c0];
      #pragma unroll
      for (int q = 0; q < 4; ++q) {
        u16x8 tv = *reinterpret_cast<const u16x8*>(tr + q * 8);
        #pragma unroll
        for (int k = 0; k < 8; ++k) a[q * 8 + k] = fmaf(sl, bf2f(tv[k]), a[q * 8 + k]);
      }
    }
    #pragma unroll
    for (int q = 0; q < 4; ++q) {
      u16x8 ov;
      #pragma unroll
      for (int k = 0; k < 8; ++k) ov[k] = f2bf(a[q * 8 + k]);
      *reinterpret_cast<u16x8*>(xw + c0 + q * 8) = ov;
    }
  }
}

// ---------------- MFMA conv 3x3 stride-1: full-row blocks (128 px) ---------
// Block = 4 waves; wave owns OCW oc x 128 px (8 pf). Staging 3x130 cols.
template <int CHUNKS, int XR, int OC, int OCW, bool AFFINE, bool GNST, bool RELU,
          int OROW>
__global__ __launch_bounds__(256) void convT_mfma(
    const u16* __restrict__ xt, const u16* __restrict__ wt,
    const float* __restrict__ bias, const float* __restrict__ gA,
    const float* __restrict__ gB, float* __restrict__ gnsum,
    u16* __restrict__ outT) {
  constexpr int ICPAD = CHUNKS * 32;
  constexpr int OCB = 4 * OCW;
  constexpr int NOF = OCW / 16;
  __shared__ u16 lb[15600];    // 390 rc * 5 slots * 8 u16 = 31.2 KB
  const int tid = threadIdx.x;
  const int lane = tid & 63;
  const int w = tid >> 6;
  const int oh = blockIdx.x;
  const int oc0 = blockIdx.y * OCB + w * OCW;
  const int b = blockIdx.z;
  const int colA = lane & 15;
  const int g = lane >> 4;

  f32x4 acc[NOF][8];
  #pragma unroll
  for (int of = 0; of < NOF; ++of) {
    f32x4 bv;
    #pragma unroll
    for (int r = 0; r < 4; ++r) bv[r] = bias[oc0 + of * 16 + g * 4 + r];
    #pragma unroll
    for (int pf = 0; pf < 8; ++pf) acc[of][pf] = bv;
  }

  const u16* xtb = xt + (size_t)b * HW * XR;
  for (int ch = 0; ch < CHUNKS; ++ch) {
    __syncthreads();
    // stage 1560 slots = 3 rows x 130 cols x 4 icg, 16B each
    for (int slot = tid; slot < 1560; slot += 256) {
      int icg = slot & 3;
      int rc = slot >> 2;
      int col = rc % 130;
      int row = rc / 130;
      int ih = oh + row - 1;
      int ip = col - 1;
      int chb = ch * 32 + icg * 8;
      u16x8 v = {0, 0, 0, 0, 0, 0, 0, 0};
      if ((unsigned)ih < 128u && (unsigned)ip < 128u && chb + 8 <= XR) {
        v = *reinterpret_cast<const u16x8*>(xtb + (size_t)(ih * 128 + ip) * XR + chb);
        if constexpr (AFFINE) {
          const float* ga = gA + b * 256 + chb;
          const float* gb2 = gB + b * 256 + chb;
          #pragma unroll
          for (int k = 0; k < 8; ++k)
            v[k] = f2bf(fmaxf(fmaf(bf2f(v[k]), ga[k], gb2[k]), 0.f));
        }
      }
      *reinterpret_cast<u16x8*>(&lb[(rc * 5 + icg) << 3]) = v;
    }
    __syncthreads();
    #pragma unroll
    for (int kk = 0; kk < 9; ++kk) {
      const int kh = kk / 3, kw = kk - kh * 3;
      short8 afrag[NOF];
      const u16* wb = wt + ((size_t)kk * OC + oc0 + colA) * ICPAD + ch * 32 + g * 8;
      #pragma unroll
      for (int of = 0; of < NOF; ++of)
        afrag[of] = *reinterpret_cast<const short8*>(wb + (size_t)of * 16 * ICPAD);
      #pragma unroll
      for (int pf = 0; pf < 8; ++pf) {
        int colx = pf * 16 + colA + kw;
        short8 bfrag = *reinterpret_cast<const short8*>(
            &lb[((kh * 130 + colx) * 5 + g) << 3]);
        #pragma unroll
        for (int of = 0; of < NOF; ++of)
          acc[of][pf] = __builtin_amdgcn_mfma_f32_16x16x32_bf16(
              afrag[of], bfrag, acc[of][pf], 0, 0, 0);
      }
    }
  }
  #pragma unroll
  for (int of = 0; of < NOF; ++of) {
    float s = 0.f, ss = 0.f;
    #pragma unroll
    for (int pf = 0; pf < 8; ++pf) {
      int px = oh * 128 + pf * 16 + colA;
      u16x4 o;
      #pragma unroll
      for (int r = 0; r < 4; ++r) {
        float v = acc[of][pf][r];
        if constexpr (RELU) v = fmaxf(v, 0.f);
        if constexpr (GNST) { s += v; ss = fmaf(v, v, ss); }
        o[r] = f2bf(v);
      }
      *reinterpret_cast<u16x4*>(
          outT + ((size_t)b * HW + px) * OROW + oc0 + of * 16 + g * 4) = o;
    }
    if constexpr (GNST) {
      #pragma unroll
      for (int off2 = 1; off2 < 16; off2 <<= 1) {
        s += __shfl_xor(s, off2);
        ss += __shfl_xor(ss, off2);
      }
      s += __shfl_xor(s, 16);
      ss += __shfl_xor(ss, 16);
      if (colA == 0 && (g & 1) == 0) {
        int grp = (oc0 + of * 16 + g * 4) >> 3;
        atomicAdd(gnsum + ((size_t)b * 32 + grp) * 2, s);
        atomicAdd(gnsum + ((size_t)b * 32 + grp) * 2 + 1, ss);
      }
    }
  }
}

// ---------------- GN finalize: sums -> per (b,c) affine a,b ----------------
__global__ __launch_bounds__(256) void gn_fin(
    const float* __restrict__ gnsum, const float* __restrict__ gg,
    const float* __restrict__ gb, float* __restrict__ gA,
    float* __restrict__ gB) {
  int b = blockIdx.x, c = threadIdx.x;
  int grp = c >> 3;
  float s = gnsum[((size_t)b * 32 + grp) * 2];
  float ss = gnsum[((size_t)b * 32 + grp) * 2 + 1];
  float m = s * (1.f / 131072.f);
  float var = ss * (1.f / 131072.f) - m * m;
  float istd = rsqrtf(var + 1e-5f);
  float a = istd * gg[c];
  gA[b * 256 + c] = a;
  gB[b * 256 + c] = gb[c] - m * a;
}

// ---------------- d3: 1x1 conv 64->1 on y2T [p][64] ----------------
__global__ __launch_bounds__(256) void d3_kernel(
    const u16* __restrict__ y2t, const float* __restrict__ w3,
    const float* __restrict__ b3, float* __restrict__ y3) {
  int idx = blockIdx.x * 256 + threadIdx.x;
  const u16* r = y2t + (size_t)idx * 64;
  float acc = b3[0];
  #pragma unroll
  for (int cg = 0; cg < 8; ++cg) {
    u16x8 v = *reinterpret_cast<const u16x8*>(r + cg * 8);
    #pragma unroll
    for (int k = 0; k < 8; ++k) acc = fmaf(bf2f(v[k]), w3[cg * 8 + k], acc);
  }
  y3[idx] = acc;
}

// ---------------- bilinear upsample 128 -> 512 ----------------
__global__ __launch_bounds__(256) void upsample_kernel(
    const float* __restrict__ y3, float* __restrict__ out) {
  int idx = blockIdx.x * 256 + threadIdx.x;
  int b = idx >> 18;
  int rem = idx & 262143;
  int Y = rem >> 9, X = rem & 511;
  float sy = (Y + 0.5f) * 0.25f - 0.5f;
  float sx = (X + 0.5f) * 0.25f - 0.5f;
  float y0f = floorf(sy), x0f = floorf(sx);
  float fy = sy - y0f, fx = sx - x0f;
  int y0 = (int)y0f, x0 = (int)x0f;
  int y0c = max(y0, 0), y1c = min(y0 + 1, 127);
  int x0c = max(x0, 0), x1c = min(x0 + 1, 127);
  const float* yb = y3 + (size_t)b * HW;
  float v00 = yb[y0c * 128 + x0c], v01 = yb[y0c * 128 + x1c];
  float v10 = yb[y1c * 128 + x0c], v11 = yb[y1c * 128 + x1c];
  out[idx] = (1.f - fy) * ((1.f - fx) * v00 + fx * v01) +
             fy * ((1.f - fx) * v10 + fx * v11);
}

extern "C" void kernel_launch(void* const* d_in, const int* in_sizes, int n_in,
                              void* d_out, int out_size, void* d_ws, size_t ws_size,
                              hipStream_t stream) {
  const float* images  = (const float*)d_in[0];
  const int*   tokens  = (const int*)d_in[1];
  const float* tok512  = (const float*)d_in[2];
  const float* conv1_w = (const float*)d_in[3];
  const float* conv1_b = (const float*)d_in[4];
  const float* conv2_w = (const float*)d_in[5];
  const float* conv2_b = (const float*)d_in[6];
  const float* sp1_w   = (const float*)d_in[7];
  const float* sp1_b   = (const float*)d_in[8];
  const float* sp2_w   = (const float*)d_in[9];
  const float* sp2_b   = (const float*)d_in[10];
  const float* proj_w  = (const float*)d_in[11];
  const float* proj_b  = (const float*)d_in[12];
  const float* gate_w  = (const float*)d_in[13];
  const float* gate_b  = (const float*)d_in[14];
  const float* d1_w    = (const float*)d_in[15];
  const float* d1_b    = (const float*)d_in[16];
  const float* gn_g    = (const float*)d_in[17];
  const float* gn_b    = (const float*)d_in[18];
  const float* d2_w    = (const float*)d_in[19];
  const float* d2_b    = (const float*)d_in[20];
  const float* d3_w    = (const float*)d_in[21];
  const float* d3_b    = (const float*)d_in[22];

  float* outp = (float*)d_out;
  if (ws_size < WS_BYTES_NEEDED) {
    float v = 10000.0f + (float)(ws_size >> 20);
    fill_kernel<<<(out_size + 255) / 256, 256, 0, stream>>>(outp, out_size, v);
    return;
  }

  char* wsb = (char*)d_ws;
  u16*   xt    = (u16*)(wsb + OFF_XT);
  u16*   x1t   = (u16*)(wsb + OFF_B);
  float* tokb  = (float*)(wsb + OFF_B);
  float* gvecb = (float*)(wsb + OFF_B + OFF_GVECB);
  u16*   pgb   = (u16*)(wsb + OFF_PG);
  u16*   y1t   = (u16*)(wsb + OFF_B);
  float* gnsum = (float*)(wsb + OFF_GNSUM);
  u16*   y2t   = (u16*)(wsb + OFF_Y2T);
  float* gA    = (float*)(wsb + OFF_GA);
  float* gB    = (float*)(wsb + OFF_GB);
  float* y3    = (float*)(wsb + OFF_Y3);

  u16* wt1  = (u16*)d_out;
  u16* wt2  = (u16*)((char*)d_out + WT1_BYTES);
  u16* wtc2 = (u16*)((char*)d_out + WT1_BYTES + WT2_BYTES);

  prep_wt<<<(9 * 256 * 544 + 255) / 256, 256, 0, stream>>>(
      d1_w, wt1, 256, 513, 544, 9 * 256 * 544);
  prep_wt<<<(9 * 64 * 256 + 255) / 256, 256, 0, stream>>>(
      d2_w, wt2, 64, 256, 256, 9 * 64 * 256);
  prep_wt<<<(9 * 256 * 64 + 255) / 256, 256, 0, stream>>>(
      conv2_w, wtc2, 256, 64, 64, 9 * 256 * 64);
  zero_gnsum<<<1, 512, 0, stream>>>(gnsum);

  pos_xt<<<256, 256, 0, stream>>>(sp1_w, sp1_b, sp2_w, sp2_b, xt);
  conv1_kernel<<<dim3(256, 8), 256, 0, stream>>>(images, conv1_w, conv1_b, x1t);
  conv2_mfma<<<dim3(256, 1, 8), 256, 0, stream>>>(x1t, wtc2, conv2_b, xt);
  token_kernel<<<BB * LL, 256, 0, stream>>>(tok512, proj_w, proj_b, gate_w,
                                            gate_b, tokb);
  gvec_kernel<<<BB, 256, 0, stream>>>(tokb, tokens, gvecb);
  attn_score<<<dim3(256, BB), 256, 0, stream>>>(xt, tokb, tokens, gvecb, pgb);
  attn_ctx<<<dim3(64, BB), 256, 0, stream>>>(xt, tokb, pgb);
  // d1: 513->256 MFMA, full-row blocks (128 px), OCW=64, fused GN stats
  convT_mfma<17, XROW, 256, 64, false, true, false, 256>
      <<<dim3(128, 1, 8), 256, 0, stream>>>(xt, wt1, d1_b, nullptr, nullptr,
                                            gnsum, y1t);
  gn_fin<<<8, 256, 0, stream>>>(gnsum, gn_g, gn_b, gA, gB);
  // d2: 256->64 MFMA, full-row blocks, GN-affine+ReLU at staging, y2T [p][64]
  convT_mfma<8, 256, 64, 16, true, false, true, 64>
      <<<dim3(128, 1, 8), 256, 0, stream>>>(y1t, wt2, d2_b, gA, gB, nullptr, y2t);
  d3_kernel<<<512, 256, 0, stream>>>(y2t, d3_w, d3_b, y3);
  upsample_kernel<<<8192, 256, 0, stream>>>(y3, outp);
}

// Round 15
// 1250.720 us; speedup vs baseline: 1.1452x; 1.1452x over previous
//
#include <hip/hip_runtime.h>
#include <math.h>

typedef unsigned short u16;
typedef __attribute__((ext_vector_type(4))) unsigned short u16x4;
typedef __attribute__((ext_vector_type(8))) unsigned short u16x8;
typedef __attribute__((ext_vector_type(8))) short short8;   // MFMA A/B frag (8 bf16)
typedef __attribute__((ext_vector_type(4))) float f32x4;    // MFMA C/D frag

#define BB 8
#define CC 256
#define LL 77
#define HW 16384    // 128*128
#define XROW 520    // XT row stride in ch (513 padded to 8-multiple)

__device__ __forceinline__ float bf2f(u16 h) {
  return __uint_as_float(((unsigned)h) << 16);
}
__device__ __forceinline__ u16 f2bf(float f) {   // round-to-nearest-even
  unsigned u = __float_as_uint(f);
  unsigned r = (u + 0x7fffu + ((u >> 16) & 1u)) >> 16;
  return (u16)r;
}

// ---------------- workspace layout (BYTE offsets) ----------------
static const size_t OFF_XT    = 0;
static const size_t OFF_B     = 136314880;
static const size_t OFF_GVECB = 630784;          // relative to OFF_B
static const size_t OFF_GNSUM = 203423744;
static const size_t WS_BYTES_NEEDED = 203425792;  // ~194.0 MiB (known to fit)
// Region-A reuse offsets (absolute):
static const size_t OFF_Y2T = 0;
static const size_t OFF_GA  = 16777216;
static const size_t OFF_GB  = 16785408;
static const size_t OFF_Y3  = 16793600;
// d_out scratch: wt1, wt2, wtc2 (dead until final upsample)
static const size_t WT1_BYTES = 9u * 256u * 544u * 2u;   // 2,506,752
static const size_t WT2_BYTES = 9u * 64u * 256u * 2u;    // 294,912

// ---------------- diagnostic fill (only if ws too small) ----------------
__global__ __launch_bounds__(256) void fill_kernel(float* __restrict__ out,
                                                   int n, float v) {
  int i = blockIdx.x * 256 + threadIdx.x;
  if (i < n) out[i] = v;
}

__global__ __launch_bounds__(512) void zero_gnsum(float* __restrict__ g) {
  g[threadIdx.x] = 0.f;
}

// ---------------- weight transpose: w[oc][ic][3][3] f32 -> wt[kk][oc][icpad] bf16
__global__ __launch_bounds__(256) void prep_wt(
    const float* __restrict__ w, u16* __restrict__ wt,
    int OC, int ICSRC, int ICPAD, int total) {
  int idx = blockIdx.x * 256 + threadIdx.x;
  if (idx >= total) return;
  int ic = idx % ICPAD;
  int oc = (idx / ICPAD) % OC;
  int kk = idx / (ICPAD * OC);
  float v = 0.f;
  if (ic < ICSRC) v = w[((size_t)oc * ICSRC + ic) * 9 + kk];
  wt[idx] = f2bf(v);
}

// ---------------- pos -> XT img channels directly (all 8 batches) ----------
__global__ __launch_bounds__(256) void pos_xt(
    const float* __restrict__ sp1_w, const float* __restrict__ sp1_b,
    const float* __restrict__ sp2_w, const float* __restrict__ sp2_b,
    u16* __restrict__ xt) {
  __shared__ float hid[64 * 64];   // [pxl][h] 16 KB
  __shared__ u16 pv[64 * 256];     // [pxl][c] 32 KB
  const int tid = threadIdx.x;
  const int px0 = blockIdx.x * 64;
  #pragma unroll
  for (int i = 0; i < 16; ++i) {
    int slot = i * 256 + tid;
    int pxl = slot >> 6, h = slot & 63;
    int px = px0 + pxl;
    float xx = -1.f + (px & 127) * (2.f / 127.f);
    float yy = -1.f + (px >> 7) * (2.f / 127.f);
    hid[slot] = fmaxf(sp1_w[2 * h] * xx + sp1_w[2 * h + 1] * yy + sp1_b[h], 0.f);
  }
  float wr[64];
  #pragma unroll
  for (int q = 0; q < 16; ++q) {
    float4 v = *reinterpret_cast<const float4*>(sp2_w + tid * 64 + q * 4);
    wr[q * 4] = v.x; wr[q * 4 + 1] = v.y; wr[q * 4 + 2] = v.z; wr[q * 4 + 3] = v.w;
  }
  const float sb = sp2_b[tid];
  __syncthreads();
  for (int pxl = 0; pxl < 64; ++pxl) {
    float acc = sb;
    const float* hr = &hid[pxl * 64];
    #pragma unroll
    for (int h = 0; h < 64; ++h) acc = fmaf(wr[h], hr[h], acc);
    pv[pxl * 256 + tid] = f2bf(acc);
  }
  __syncthreads();
  for (int b = 0; b < BB; ++b) {
    u16* xb = xt + ((size_t)b * HW + px0) * XROW;
    #pragma unroll
    for (int it = 0; it < 8; ++it) {
      int slot = it * 256 + tid;
      int pxl = slot >> 5, cg = slot & 31;
      *reinterpret_cast<u16x8*>(xb + (size_t)pxl * XROW + cg * 8) =
          *reinterpret_cast<const u16x8*>(&pv[pxl * 256 + cg * 8]);
    }
  }
}

// ---------------- conv1: 3->64, stride 2, relu; writes x1T [px][64] ---------
__global__ __launch_bounds__(256) void conv1_kernel(
    const float* __restrict__ in, const float* __restrict__ w,
    const float* __restrict__ bias, u16* __restrict__ x1t) {
  __shared__ float wl[27 * 64];   // [t][oc]
  __shared__ float bl[64];
  const int tid = threadIdx.x;
  const int oh = blockIdx.x;
  const int b = blockIdx.y;
  for (int i = tid; i < 27 * 64; i += 256) {
    int oc = i & 63;
    int t = i >> 6;
    wl[t * 64 + oc] = w[oc * 27 + t];
  }
  if (tid < 64) bl[tid] = bias[tid];
  __syncthreads();
  const int ow = tid;
  float acc[64];
  #pragma unroll
  for (int oc = 0; oc < 64; ++oc) acc[oc] = bl[oc];
  for (int ic = 0; ic < 3; ++ic) {
    #pragma unroll
    for (int kh = 0; kh < 3; ++kh) {
      int ih = 2 * oh + kh - 1;
      if ((unsigned)ih >= 512u) continue;
      const float* row = in + ((size_t)(b * 3 + ic) * 512 + ih) * 512;
      int iw = 2 * ow - 1;
      float v0 = (iw >= 0) ? row[iw] : 0.f;
      float v1 = row[iw + 1];
      float v2 = row[iw + 2];
      const float* wr = &wl[(ic * 3 + kh) * 192];
      #pragma unroll
      for (int oc = 0; oc < 64; ++oc)
        acc[oc] += v0 * wr[oc] + v1 * wr[64 + oc] + v2 * wr[128 + oc];
    }
  }
  u16* orow = x1t + ((size_t)b * 65536 + oh * 256 + ow) * 64;
  #pragma unroll
  for (int q = 0; q < 8; ++q) {
    u16x8 o;
    #pragma unroll
    for (int k = 0; k < 8; ++k) o[k] = f2bf(fmaxf(acc[q * 8 + k], 0.f));
    *reinterpret_cast<u16x8*>(orow + q * 8) = o;
  }
}

// ---------------- conv2 MFMA: 64->256, stride 2; XT[p][oc] += relu(conv) ----
__global__ __launch_bounds__(256) void conv2_mfma(
    const u16* __restrict__ x1t, const u16* __restrict__ wt,
    const float* __restrict__ bias, u16* __restrict__ xt) {
  __shared__ u16 lb[15480];   // 1935 slots * 8 u16 = 30,960 B
  const int tid = threadIdx.x;
  const int lane = tid & 63;
  const int w = tid >> 6;
  const int oh = blockIdx.x >> 1;
  const int half = blockIdx.x & 1;
  const int ow0 = half << 6;
  const int b = blockIdx.z;
  const int colA = lane & 15;
  const int g = lane >> 4;
  const int oc0w = w * 64;

  f32x4 acc[4][4];
  #pragma unroll
  for (int of = 0; of < 4; ++of) {
    f32x4 bv;
    #pragma unroll
    for (int r = 0; r < 4; ++r) bv[r] = bias[oc0w + of * 16 + g * 4 + r];
    #pragma unroll
    for (int pf = 0; pf < 4; ++pf) acc[of][pf] = bv;
  }

  const u16* xb = x1t + (size_t)b * 65536 * 64;
  for (int ch = 0; ch < 2; ++ch) {
    __syncthreads();
    for (int slot = tid; slot < 1548; slot += 256) {
      int icg = slot & 3;
      int rc = slot >> 2;
      int kh, ip;
      if (rc < 192) {
        kh = rc / 64; int i = rc - kh * 64; ip = (ow0 << 1) + 2 * i;
      } else {
        int rc2 = rc - 192; kh = rc2 / 65; int j = rc2 - kh * 65;
        ip = (ow0 << 1) - 1 + 2 * j;
      }
      int ih = 2 * oh + kh - 1;
      u16x8 v = {0, 0, 0, 0, 0, 0, 0, 0};
      if ((unsigned)ih < 256u && (unsigned)ip < 256u)
        v = *reinterpret_cast<const u16x8*>(
            xb + ((size_t)(ih * 256 + ip)) * 64 + ch * 32 + icg * 8);
      *reinterpret_cast<u16x8*>(&lb[(rc * 5 + icg) << 3]) = v;
    }
    __syncthreads();
    #pragma unroll
    for (int kk = 0; kk < 9; ++kk) {
      const int kh = kk / 3, kw = kk - kh * 3;
      short8 afrag[4];
      const u16* wb = wt + ((size_t)kk * 256 + oc0w + colA) * 64 + ch * 32 + g * 8;
      #pragma unroll
      for (int of = 0; of < 4; ++of)
        afrag[of] = *reinterpret_cast<const short8*>(wb + (size_t)of * 16 * 64);
      #pragma unroll
      for (int pf = 0; pf < 4; ++pf) {
        int ow = pf * 16 + colA;
        int rc = (kw == 1) ? (kh * 64 + ow) : (192 + kh * 65 + ow + (kw >> 1));
        short8 bfrag = *reinterpret_cast<const short8*>(&lb[(rc * 5 + g) << 3]);
        #pragma unroll
        for (int of = 0; of < 4; ++of)
          acc[of][pf] = __builtin_amdgcn_mfma_f32_16x16x32_bf16(
              afrag[of], bfrag, acc[of][pf], 0, 0, 0);
      }
    }
  }
  #pragma unroll
  for (int of = 0; of < 4; ++of) {
    #pragma unroll
    for (int pf = 0; pf < 4; ++pf) {
      int px = oh * 128 + ow0 + pf * 16 + colA;
      int oc = oc0w + of * 16 + g * 4;
      u16* dst = xt + ((size_t)b * HW + px) * XROW + oc;
      u16x4 pz = *reinterpret_cast<const u16x4*>(dst);
      u16x4 o;
      #pragma unroll
      for (int r = 0; r < 4; ++r)
        o[r] = f2bf(fmaxf(acc[of][pf][r], 0.f) + bf2f(pz[r]));
      *reinterpret_cast<u16x4*>(dst) = o;
    }
  }
}

// ---------------- token pipeline: proj -> gate -> l2norm (f32 out) ----------
__global__ __launch_bounds__(256) void token_kernel(
    const float* __restrict__ tok512, const float* __restrict__ proj_w,
    const float* __restrict__ proj_b, const float* __restrict__ gate_w,
    const float* __restrict__ gate_b, float* __restrict__ tok_out) {
  __shared__ float t512[512];
  __shared__ float prj[256];
  __shared__ float red[4];
  int bl = blockIdx.x;
  int c = threadIdx.x;
  const float* trow = tok512 + (size_t)bl * 512;
  t512[c] = trow[c];
  t512[c + 256] = trow[c + 256];
  __syncthreads();
  float acc = proj_b[c];
  #pragma unroll 4
  for (int k = 0; k < 512; ++k) acc = fmaf(t512[k], proj_w[k * 256 + c], acc);
  prj[c] = acc;
  __syncthreads();
  float acc2 = gate_b[c];
  #pragma unroll 4
  for (int k = 0; k < 256; ++k) acc2 = fmaf(prj[k], gate_w[k * 256 + c], acc2);
  float g = 1.f / (1.f + __expf(-acc2));
  float tv = g * acc;
  float ss = tv * tv;
  #pragma unroll
  for (int off = 1; off < 64; off <<= 1) ss += __shfl_xor(ss, off);
  if ((c & 63) == 0) red[c >> 6] = ss;
  __syncthreads();
  float tot = red[0] + red[1] + red[2] + red[3];
  tok_out[(size_t)bl * 256 + c] = tv * (1.f / fmaxf(sqrtf(tot), 1e-12f));
}

// ---------------- gvec ----------------
__global__ __launch_bounds__(256) void gvec_kernel(
    const float* __restrict__ tok, const int* __restrict__ tokens,
    float* __restrict__ gvec) {
  __shared__ float red[4];
  int b = blockIdx.x, c = threadIdx.x;
  float s = 0.f;
  for (int l = 0; l < LL; ++l) {
    if (tokens[b * LL + l] != 0) s += tok[((size_t)b * LL + l) * 256 + c];
  }
  float ss = s * s;
  #pragma unroll
  for (int off = 1; off < 64; off <<= 1) ss += __shfl_xor(ss, off);
  if ((c & 63) == 0) red[c >> 6] = ss;
  __syncthreads();
  float tot = red[0] + red[1] + red[2] + red[3];
  gvec[b * 256 + c] = s * (1.f / fmaxf(sqrtf(tot), 1e-12f));
}

// ---------------- fused attention: scores+softmax -> P in LDS -> ctx -------
// Phase 1 (4 thr/px, s[20] regs): scores, softmax, P -> pl (LDS), sim -> XT.
// Phase 2: thread (pxl,q) computes ctx channels [q*64, q*64+64) from pl x ltok
// (ltok is already resident in LDS) and writes XT directly. No global P.
__global__ __launch_bounds__(256, 1) void attn_fused(
    u16* __restrict__ xt, const float* __restrict__ tok,
    const int* __restrict__ tokens, const float* __restrict__ gvec) {
  __shared__ u16 ltok[LL * 256];   // bf16 tokens (39.4 KB)
  __shared__ u16 pl[64 * 104];     // P [px][l] (13.3 KB)
  __shared__ float lgv[256];
  __shared__ u16 lval[LL + 3];
  const int tid = threadIdx.x;
  const int b = blockIdx.y;
  const int px0 = blockIdx.x * 64;
  for (int slot = tid; slot < LL * 32; slot += 256) {
    int l = slot >> 5, cg = slot & 31;
    const float* tp = tok + ((size_t)b * LL + l) * 256 + cg * 8;
    float4 t0 = *reinterpret_cast<const float4*>(tp);
    float4 t1 = *reinterpret_cast<const float4*>(tp + 4);
    u16x8 v = {f2bf(t0.x), f2bf(t0.y), f2bf(t0.z), f2bf(t0.w),
               f2bf(t1.x), f2bf(t1.y), f2bf(t1.z), f2bf(t1.w)};
    *reinterpret_cast<u16x8*>(&ltok[l * 256 + cg * 8]) = v;
  }
  if (tid < LL) lval[tid] = (tokens[b * LL + tid] != 0) ? 1 : 0;
  lgv[tid] = gvec[b * 256 + tid];
  __syncthreads();
  const int pxl = tid >> 2;
  const int q = tid & 3;
  const int p = px0 + pxl;
  const u16* xr = xt + ((size_t)b * HW + p) * XROW;
  float s[20];
  #pragma unroll
  for (int i = 0; i < 20; ++i) s[i] = 0.f;
  float ssum = 0.f, simacc = 0.f;
  #pragma unroll 1
  for (int c0 = 0; c0 < 256; c0 += 32) {
    float x[32];
    #pragma unroll
    for (int qq = 0; qq < 4; ++qq) {
      u16x8 iv = *reinterpret_cast<const u16x8*>(xr + c0 + qq * 8);
      #pragma unroll
      for (int k = 0; k < 8; ++k) x[qq * 8 + k] = bf2f(iv[k]);
    }
    #pragma unroll
    for (int k = 0; k < 32; ++k) {
      ssum = fmaf(x[k], x[k], ssum);
      simacc = fmaf(x[k], lgv[c0 + k], simacc);
    }
    #pragma unroll
    for (int li = 0; li < 20; ++li) {
      int l = li * 4 + q;
      if (l < LL) {
        const u16* tr = &ltok[l * 256 + c0];
        float a2 = s[li];
        #pragma unroll
        for (int qq = 0; qq < 4; ++qq) {
          u16x8 tv = *reinterpret_cast<const u16x8*>(tr + qq * 8);
          #pragma unroll
          for (int k = 0; k < 8; ++k) a2 = fmaf(x[qq * 8 + k], bf2f(tv[k]), a2);
        }
        s[li] = a2;
      }
    }
  }
  const float invn = 1.f / fmaxf(sqrtf(ssum), 1e-12f);
  const float sc = invn * 0.0625f;
  float m = -1e30f;
  #pragma unroll
  for (int li = 0; li < 20; ++li) {
    int l = li * 4 + q;
    float v = (l < LL) ? (lval[l] ? s[li] * sc : -10000.f) : -1e30f;
    s[li] = v;
    m = fmaxf(m, v);
  }
  m = fmaxf(m, __shfl_xor(m, 1));
  m = fmaxf(m, __shfl_xor(m, 2));
  float sum = 0.f;
  #pragma unroll
  for (int li = 0; li < 20; ++li) {
    float e = __expf(s[li] - m);   // pad rows: exp(-1e30 - m) = 0
    s[li] = e;
    sum += e;
  }
  sum += __shfl_xor(sum, 1);
  sum += __shfl_xor(sum, 2);
  const float rs = 1.f / sum;
  #pragma unroll
  for (int li = 0; li < 20; ++li) {
    int l = li * 4 + q;
    if (l < LL) pl[pxl * 104 + l] = f2bf(s[li] * rs);
  }
  if (q == 0) {
    u16x8 sv = {f2bf(simacc * invn), 0, 0, 0, 0, 0, 0, 0};
    *reinterpret_cast<u16x8*>(xt + ((size_t)b * HW + p) * XROW + 512) = sv;
  }
  __syncthreads();
  // ---- phase 2: ctx = P @ tok, channels [q*64, q*64+64) per thread ----
  const int cbase = q * 64;
  float a[64];
  #pragma unroll
  for (int k = 0; k < 64; ++k) a[k] = 0.f;
  #pragma unroll 1
  for (int l = 0; l < LL; ++l) {
    float sl = bf2f(pl[pxl * 104 + l]);
    const u16* tr = &ltok[l * 256 + cbase];
    #pragma unroll
    for (int qq = 0; qq < 8; ++qq) {
      u16x8 tv = *reinterpret_cast<const u16x8*>(tr + qq * 8);
      #pragma unroll
      for (int k = 0; k < 8; ++k)
        a[qq * 8 + k] = fmaf(sl, bf2f(tv[k]), a[qq * 8 + k]);
    }
  }
  u16* xw = xt + ((size_t)b * HW + p) * XROW + 256 + cbase;
  #pragma unroll
  for (int qq = 0; qq < 8; ++qq) {
    u16x8 ov;
    #pragma unroll
    for (int k = 0; k < 8; ++k) ov[k] = f2bf(a[qq * 8 + k]);
    *reinterpret_cast<u16x8*>(xw + qq * 8) = ov;
  }
}

// ---------------- MFMA conv 3x3 stride-1 on transposed input (R11 config) ---
template <int CHUNKS, int XR, int OC, int OCW, bool AFFINE, bool GNST, bool RELU,
          int OROW>
__global__ __launch_bounds__(256) void convT_mfma(
    const u16* __restrict__ xt, const u16* __restrict__ wt,
    const float* __restrict__ bias, const float* __restrict__ gA,
    const float* __restrict__ gB, float* __restrict__ gnsum,
    u16* __restrict__ outT) {
  constexpr int ICPAD = CHUNKS * 32;
  constexpr int OCB = 4 * OCW;
  constexpr int NOF = OCW / 16;
  __shared__ u16 lb[7920];
  const int tid = threadIdx.x;
  const int lane = tid & 63;
  const int w = tid >> 6;
  const int oh = blockIdx.x >> 1;
  const int ow0 = (blockIdx.x & 1) << 6;
  const int oc0 = blockIdx.y * OCB + w * OCW;
  const int b = blockIdx.z;
  const int colA = lane & 15;
  const int g = lane >> 4;

  f32x4 acc[NOF][4];
  #pragma unroll
  for (int of = 0; of < NOF; ++of) {
    f32x4 bv;
    #pragma unroll
    for (int r = 0; r < 4; ++r) bv[r] = bias[oc0 + of * 16 + g * 4 + r];
    #pragma unroll
    for (int pf = 0; pf < 4; ++pf) acc[of][pf] = bv;
  }

  const u16* xtb = xt + (size_t)b * HW * XR;
  for (int ch = 0; ch < CHUNKS; ++ch) {
    __syncthreads();
    #pragma unroll
    for (int it = 0; it < 4; ++it) {
      int slot = it * 256 + tid;
      if (slot < 792) {
        int icg = slot & 3;
        int rc = slot >> 2;
        int col = rc % 66;
        int row = rc / 66;
        int ih = oh + row - 1;
        int ip = ow0 - 1 + col;
        int chb = ch * 32 + icg * 8;
        u16x8 v = {0, 0, 0, 0, 0, 0, 0, 0};
        if ((unsigned)ih < 128u && (unsigned)ip < 128u && chb + 8 <= XR) {
          v = *reinterpret_cast<const u16x8*>(xtb + (size_t)(ih * 128 + ip) * XR + chb);
          if constexpr (AFFINE) {
            const float* ga = gA + b * 256 + chb;
            const float* gb2 = gB + b * 256 + chb;
            #pragma unroll
            for (int k = 0; k < 8; ++k)
              v[k] = f2bf(fmaxf(fmaf(bf2f(v[k]), ga[k], gb2[k]), 0.f));
          }
        }
        *reinterpret_cast<u16x8*>(&lb[(rc * 5 + icg) << 3]) = v;
      }
    }
    __syncthreads();
    #pragma unroll
    for (int kk = 0; kk < 9; ++kk) {
      const int kh = kk / 3, kw = kk - kh * 3;
      short8 afrag[NOF];
      const u16* wb = wt + ((size_t)kk * OC + oc0 + colA) * ICPAD + ch * 32 + g * 8;
      #pragma unroll
      for (int of = 0; of < NOF; ++of)
        afrag[of] = *reinterpret_cast<const short8*>(wb + (size_t)of * 16 * ICPAD);
      #pragma unroll
      for (int pf = 0; pf < 4; ++pf) {
        int colx = pf * 16 + colA + kw;
        short8 bfrag = *reinterpret_cast<const short8*>(
            &lb[((kh * 66 + colx) * 5 + g) << 3]);
        #pragma unroll
        for (int of = 0; of < NOF; ++of)
          acc[of][pf] = __builtin_amdgcn_mfma_f32_16x16x32_bf16(
              afrag[of], bfrag, acc[of][pf], 0, 0, 0);
      }
    }
  }
  #pragma unroll
  for (int of = 0; of < NOF; ++of) {
    float s = 0.f, ss = 0.f;
    #pragma unroll
    for (int pf = 0; pf < 4; ++pf) {
      int px = oh * 128 + ow0 + pf * 16 + colA;
      u16x4 o;
      #pragma unroll
      for (int r = 0; r < 4; ++r) {
        float v = acc[of][pf][r];
        if constexpr (RELU) v = fmaxf(v, 0.f);
        if constexpr (GNST) { s += v; ss = fmaf(v, v, ss); }
        o[r] = f2bf(v);
      }
      *reinterpret_cast<u16x4*>(
          outT + ((size_t)b * HW + px) * OROW + oc0 + of * 16 + g * 4) = o;
    }
    if constexpr (GNST) {
      #pragma unroll
      for (int off2 = 1; off2 < 16; off2 <<= 1) {
        s += __shfl_xor(s, off2);
        ss += __shfl_xor(ss, off2);
      }
      s += __shfl_xor(s, 16);
      ss += __shfl_xor(ss, 16);
      if (colA == 0 && (g & 1) == 0) {
        int grp = (oc0 + of * 16 + g * 4) >> 3;
        atomicAdd(gnsum + ((size_t)b * 32 + grp) * 2, s);
        atomicAdd(gnsum + ((size_t)b * 32 + grp) * 2 + 1, ss);
      }
    }
  }
}

// ---------------- GN finalize: sums -> per (b,c) affine a,b ----------------
__global__ __launch_bounds__(256) void gn_fin(
    const float* __restrict__ gnsum, const float* __restrict__ gg,
    const float* __restrict__ gb, float* __restrict__ gA,
    float* __restrict__ gB) {
  int b = blockIdx.x, c = threadIdx.x;
  int grp = c >> 3;
  float s = gnsum[((size_t)b * 32 + grp) * 2];
  float ss = gnsum[((size_t)b * 32 + grp) * 2 + 1];
  float m = s * (1.f / 131072.f);
  float var = ss * (1.f / 131072.f) - m * m;
  float istd = rsqrtf(var + 1e-5f);
  float a = istd * gg[c];
  gA[b * 256 + c] = a;
  gB[b * 256 + c] = gb[c] - m * a;
}

// ---------------- d3: 1x1 conv 64->1 on y2T [p][64] ----------------
__global__ __launch_bounds__(256) void d3_kernel(
    const u16* __restrict__ y2t, const float* __restrict__ w3,
    const float* __restrict__ b3, float* __restrict__ y3) {
  int idx = blockIdx.x * 256 + threadIdx.x;
  const u16* r = y2t + (size_t)idx * 64;
  float acc = b3[0];
  #pragma unroll
  for (int cg = 0; cg < 8; ++cg) {
    u16x8 v = *reinterpret_cast<const u16x8*>(r + cg * 8);
    #pragma unroll
    for (int k = 0; k < 8; ++k) acc = fmaf(bf2f(v[k]), w3[cg * 8 + k], acc);
  }
  y3[idx] = acc;
}

// ---------------- bilinear upsample 128 -> 512 ----------------
__global__ __launch_bounds__(256) void upsample_kernel(
    const float* __restrict__ y3, float* __restrict__ out) {
  int idx = blockIdx.x * 256 + threadIdx.x;
  int b = idx >> 18;
  int rem = idx & 262143;
  int Y = rem >> 9, X = rem & 511;
  float sy = (Y + 0.5f) * 0.25f - 0.5f;
  float sx = (X + 0.5f) * 0.25f - 0.5f;
  float y0f = floorf(sy), x0f = floorf(sx);
  float fy = sy - y0f, fx = sx - x0f;
  int y0 = (int)y0f, x0 = (int)x0f;
  int y0c = max(y0, 0), y1c = min(y0 + 1, 127);
  int x0c = max(x0, 0), x1c = min(x0 + 1, 127);
  const float* yb = y3 + (size_t)b * HW;
  float v00 = yb[y0c * 128 + x0c], v01 = yb[y0c * 128 + x1c];
  float v10 = yb[y1c * 128 + x0c], v11 = yb[y1c * 128 + x1c];
  out[idx] = (1.f - fy) * ((1.f - fx) * v00 + fx * v01) +
             fy * ((1.f - fx) * v10 + fx * v11);
}

extern "C" void kernel_launch(void* const* d_in, const int* in_sizes, int n_in,
                              void* d_out, int out_size, void* d_ws, size_t ws_size,
                              hipStream_t stream) {
  const float* images  = (const float*)d_in[0];
  const int*   tokens  = (const int*)d_in[1];
  const float* tok512  = (const float*)d_in[2];
  const float* conv1_w = (const float*)d_in[3];
  const float* conv1_b = (const float*)d_in[4];
  const float* conv2_w = (const float*)d_in[5];
  const float* conv2_b = (const float*)d_in[6];
  const float* sp1_w   = (const float*)d_in[7];
  const float* sp1_b   = (const float*)d_in[8];
  const float* sp2_w   = (const float*)d_in[9];
  const float* sp2_b   = (const float*)d_in[10];
  const float* proj_w  = (const float*)d_in[11];
  const float* proj_b  = (const float*)d_in[12];
  const float* gate_w  = (const float*)d_in[13];
  const float* gate_b  = (const float*)d_in[14];
  const float* d1_w    = (const float*)d_in[15];
  const float* d1_b    = (const float*)d_in[16];
  const float* gn_g    = (const float*)d_in[17];
  const float* gn_b    = (const float*)d_in[18];
  const float* d2_w    = (const float*)d_in[19];
  const float* d2_b    = (const float*)d_in[20];
  const float* d3_w    = (const float*)d_in[21];
  const float* d3_b    = (const float*)d_in[22];

  float* outp = (float*)d_out;
  if (ws_size < WS_BYTES_NEEDED) {
    float v = 10000.0f + (float)(ws_size >> 20);
    fill_kernel<<<(out_size + 255) / 256, 256, 0, stream>>>(outp, out_size, v);
    return;
  }

  char* wsb = (char*)d_ws;
  u16*   xt    = (u16*)(wsb + OFF_XT);
  u16*   x1t   = (u16*)(wsb + OFF_B);
  float* tokb  = (float*)(wsb + OFF_B);
  float* gvecb = (float*)(wsb + OFF_B + OFF_GVECB);
  u16*   y1t   = (u16*)(wsb + OFF_B);
  float* gnsum = (float*)(wsb + OFF_GNSUM);
  u16*   y2t   = (u16*)(wsb + OFF_Y2T);
  float* gA    = (float*)(wsb + OFF_GA);
  float* gB    = (float*)(wsb + OFF_GB);
  float* y3    = (float*)(wsb + OFF_Y3);

  u16* wt1  = (u16*)d_out;
  u16* wt2  = (u16*)((char*)d_out + WT1_BYTES);
  u16* wtc2 = (u16*)((char*)d_out + WT1_BYTES + WT2_BYTES);

  prep_wt<<<(9 * 256 * 544 + 255) / 256, 256, 0, stream>>>(
      d1_w, wt1, 256, 513, 544, 9 * 256 * 544);
  prep_wt<<<(9 * 64 * 256 + 255) / 256, 256, 0, stream>>>(
      d2_w, wt2, 64, 256, 256, 9 * 64 * 256);
  prep_wt<<<(9 * 256 * 64 + 255) / 256, 256, 0, stream>>>(
      conv2_w, wtc2, 256, 64, 64, 9 * 256 * 64);
  zero_gnsum<<<1, 512, 0, stream>>>(gnsum);

  pos_xt<<<256, 256, 0, stream>>>(sp1_w, sp1_b, sp2_w, sp2_b, xt);
  conv1_kernel<<<dim3(256, 8), 256, 0, stream>>>(images, conv1_w, conv1_b, x1t);
  conv2_mfma<<<dim3(256, 1, 8), 256, 0, stream>>>(x1t, wtc2, conv2_b, xt);
  token_kernel<<<BB * LL, 256, 0, stream>>>(tok512, proj_w, proj_b, gate_w,
                                            gate_b, tokb);
  gvec_kernel<<<BB, 256, 0, stream>>>(tokb, tokens, gvecb);
  attn_fused<<<dim3(256, BB), 256, 0, stream>>>(xt, tokb, tokens, gvecb);
  // d1: 513->256 MFMA (R11 config: OCW=32, 64-px blocks), fused GN stats
  convT_mfma<17, XROW, 256, 32, false, true, false, 256>
      <<<dim3(256, 2, 8), 256, 0, stream>>>(xt, wt1, d1_b, nullptr, nullptr,
                                            gnsum, y1t);
  gn_fin<<<8, 256, 0, stream>>>(gnsum, gn_g, gn_b, gA, gB);
  // d2: 256->64 MFMA, GN-affine+ReLU fused at staging, ReLU out, y2T [p][64]
  convT_mfma<8, 256, 64, 16, true, false, true, 64>
      <<<dim3(256, 1, 8), 256, 0, stream>>>(y1t, wt2, d2_b, gA, gB, nullptr, y2t);
  d3_kernel<<<512, 256, 0, stream>>>(y2t, d3_w, d3_b, y3);
  upsample_kernel<<<8192, 256, 0, stream>>>(y3, outp);
}

// Round 16
// 1096.987 us; speedup vs baseline: 1.3057x; 1.1401x over previous
//
#include <hip/hip_runtime.h>
#include <math.h>

typedef unsigned short u16;
typedef __attribute__((ext_vector_type(4))) unsigned short u16x4;
typedef __attribute__((ext_vector_type(8))) unsigned short u16x8;
typedef __attribute__((ext_vector_type(8))) short short8;   // MFMA A/B frag (8 bf16)
typedef __attribute__((ext_vector_type(4))) float f32x4;    // MFMA C/D frag

#define BB 8
#define CC 256
#define LL 77
#define HW 16384    // 128*128
#define XROW 520    // XT row stride in ch (513 padded to 8-multiple)

__device__ __forceinline__ float bf2f(u16 h) {
  return __uint_as_float(((unsigned)h) << 16);
}
__device__ __forceinline__ u16 f2bf(float f) {   // round-to-nearest-even
  unsigned u = __float_as_uint(f);
  unsigned r = (u + 0x7fffu + ((u >> 16) & 1u)) >> 16;
  return (u16)r;
}

// ---------------- workspace layout (BYTE offsets) ----------------
static const size_t OFF_XT    = 0;
static const size_t OFF_B     = 136314880;
static const size_t OFF_GVECB = 630784;          // relative to OFF_B
static const size_t OFF_GNSUM = 203423744;
static const size_t WS_BYTES_NEEDED = 203425792;  // ~194.0 MiB (known to fit)
// Region-A reuse offsets (absolute):
static const size_t OFF_Y2T = 0;
static const size_t OFF_GA  = 16777216;
static const size_t OFF_GB  = 16785408;
static const size_t OFF_Y3  = 16793600;
// d_out scratch: wt1, wt2, wtc2 (dead until final upsample)
static const size_t WT1_BYTES = 9u * 256u * 544u * 2u;   // 2,506,752
static const size_t WT2_BYTES = 9u * 64u * 256u * 2u;    // 294,912

// ---------------- diagnostic fill (only if ws too small) ----------------
__global__ __launch_bounds__(256) void fill_kernel(float* __restrict__ out,
                                                   int n, float v) {
  int i = blockIdx.x * 256 + threadIdx.x;
  if (i < n) out[i] = v;
}

__global__ __launch_bounds__(512) void zero_gnsum(float* __restrict__ g) {
  g[threadIdx.x] = 0.f;
}

// ---------------- weight transpose: w[oc][ic][3][3] f32 -> wt[kk][oc][icpad] bf16
__global__ __launch_bounds__(256) void prep_wt(
    const float* __restrict__ w, u16* __restrict__ wt,
    int OC, int ICSRC, int ICPAD, int total) {
  int idx = blockIdx.x * 256 + threadIdx.x;
  if (idx >= total) return;
  int ic = idx % ICPAD;
  int oc = (idx / ICPAD) % OC;
  int kk = idx / (ICPAD * OC);
  float v = 0.f;
  if (ic < ICSRC) v = w[((size_t)oc * ICSRC + ic) * 9 + kk];
  wt[idx] = f2bf(v);
}

// ---------------- pos -> XT img channels directly (all 8 batches) ----------
__global__ __launch_bounds__(256) void pos_xt(
    const float* __restrict__ sp1_w, const float* __restrict__ sp1_b,
    const float* __restrict__ sp2_w, const float* __restrict__ sp2_b,
    u16* __restrict__ xt) {
  __shared__ float hid[64 * 64];   // [pxl][h] 16 KB
  __shared__ u16 pv[64 * 256];     // [pxl][c] 32 KB
  const int tid = threadIdx.x;
  const int px0 = blockIdx.x * 64;
  #pragma unroll
  for (int i = 0; i < 16; ++i) {
    int slot = i * 256 + tid;
    int pxl = slot >> 6, h = slot & 63;
    int px = px0 + pxl;
    float xx = -1.f + (px & 127) * (2.f / 127.f);
    float yy = -1.f + (px >> 7) * (2.f / 127.f);
    hid[slot] = fmaxf(sp1_w[2 * h] * xx + sp1_w[2 * h + 1] * yy + sp1_b[h], 0.f);
  }
  float wr[64];
  #pragma unroll
  for (int q = 0; q < 16; ++q) {
    float4 v = *reinterpret_cast<const float4*>(sp2_w + tid * 64 + q * 4);
    wr[q * 4] = v.x; wr[q * 4 + 1] = v.y; wr[q * 4 + 2] = v.z; wr[q * 4 + 3] = v.w;
  }
  const float sb = sp2_b[tid];
  __syncthreads();
  for (int pxl = 0; pxl < 64; ++pxl) {
    float acc = sb;
    const float* hr = &hid[pxl * 64];
    #pragma unroll
    for (int h = 0; h < 64; ++h) acc = fmaf(wr[h], hr[h], acc);
    pv[pxl * 256 + tid] = f2bf(acc);
  }
  __syncthreads();
  for (int b = 0; b < BB; ++b) {
    u16* xb = xt + ((size_t)b * HW + px0) * XROW;
    #pragma unroll
    for (int it = 0; it < 8; ++it) {
      int slot = it * 256 + tid;
      int pxl = slot >> 5, cg = slot & 31;
      *reinterpret_cast<u16x8*>(xb + (size_t)pxl * XROW + cg * 8) =
          *reinterpret_cast<const u16x8*>(&pv[pxl * 256 + cg * 8]);
    }
  }
}

// ---------------- conv1: 3->64, stride 2, relu; writes x1T [px][64] ---------
__global__ __launch_bounds__(256) void conv1_kernel(
    const float* __restrict__ in, const float* __restrict__ w,
    const float* __restrict__ bias, u16* __restrict__ x1t) {
  __shared__ float wl[27 * 64];   // [t][oc]
  __shared__ float bl[64];
  const int tid = threadIdx.x;
  const int oh = blockIdx.x;
  const int b = blockIdx.y;
  for (int i = tid; i < 27 * 64; i += 256) {
    int oc = i & 63;
    int t = i >> 6;
    wl[t * 64 + oc] = w[oc * 27 + t];
  }
  if (tid < 64) bl[tid] = bias[tid];
  __syncthreads();
  const int ow = tid;
  float acc[64];
  #pragma unroll
  for (int oc = 0; oc < 64; ++oc) acc[oc] = bl[oc];
  for (int ic = 0; ic < 3; ++ic) {
    #pragma unroll
    for (int kh = 0; kh < 3; ++kh) {
      int ih = 2 * oh + kh - 1;
      if ((unsigned)ih >= 512u) continue;
      const float* row = in + ((size_t)(b * 3 + ic) * 512 + ih) * 512;
      int iw = 2 * ow - 1;
      float v0 = (iw >= 0) ? row[iw] : 0.f;
      float v1 = row[iw + 1];
      float v2 = row[iw + 2];
      const float* wr = &wl[(ic * 3 + kh) * 192];
      #pragma unroll
      for (int oc = 0; oc < 64; ++oc)
        acc[oc] += v0 * wr[oc] + v1 * wr[64 + oc] + v2 * wr[128 + oc];
    }
  }
  u16* orow = x1t + ((size_t)b * 65536 + oh * 256 + ow) * 64;
  #pragma unroll
  for (int q = 0; q < 8; ++q) {
    u16x8 o;
    #pragma unroll
    for (int k = 0; k < 8; ++k) o[k] = f2bf(fmaxf(acc[q * 8 + k], 0.f));
    *reinterpret_cast<u16x8*>(orow + q * 8) = o;
  }
}

// ---------------- conv2 MFMA: 64->256, stride 2; XT[p][oc] += relu(conv) ----
// XCD-swizzled: each XCD owns one batch (2048 blocks, 256/XCD).
__global__ __launch_bounds__(256) void conv2_mfma(
    const u16* __restrict__ x1t, const u16* __restrict__ wt,
    const float* __restrict__ bias, u16* __restrict__ xt) {
  __shared__ u16 lb[15480];   // 1935 slots * 8 u16 = 30,960 B
  const int tid = threadIdx.x;
  const int lane = tid & 63;
  const int w = tid >> 6;
  // XCD-aware swizzle (nwg = 2048, divisible by 8)
  int lin = blockIdx.x + (int)gridDim.x * blockIdx.z;
  int nwg = (int)gridDim.x * (int)gridDim.z;
  int swz = (lin & 7) * (nwg >> 3) + (lin >> 3);
  int bx = swz % (int)gridDim.x;
  int bz = swz / (int)gridDim.x;
  const int oh = bx >> 1;
  const int half = bx & 1;
  const int ow0 = half << 6;
  const int b = bz;
  const int colA = lane & 15;
  const int g = lane >> 4;
  const int oc0w = w * 64;

  f32x4 acc[4][4];
  #pragma unroll
  for (int of = 0; of < 4; ++of) {
    f32x4 bv;
    #pragma unroll
    for (int r = 0; r < 4; ++r) bv[r] = bias[oc0w + of * 16 + g * 4 + r];
    #pragma unroll
    for (int pf = 0; pf < 4; ++pf) acc[of][pf] = bv;
  }

  const u16* xb = x1t + (size_t)b * 65536 * 64;
  for (int ch = 0; ch < 2; ++ch) {
    __syncthreads();
    for (int slot = tid; slot < 1548; slot += 256) {
      int icg = slot & 3;
      int rc = slot >> 2;
      int kh, ip;
      if (rc < 192) {
        kh = rc / 64; int i = rc - kh * 64; ip = (ow0 << 1) + 2 * i;
      } else {
        int rc2 = rc - 192; kh = rc2 / 65; int j = rc2 - kh * 65;
        ip = (ow0 << 1) - 1 + 2 * j;
      }
      int ih = 2 * oh + kh - 1;
      u16x8 v = {0, 0, 0, 0, 0, 0, 0, 0};
      if ((unsigned)ih < 256u && (unsigned)ip < 256u)
        v = *reinterpret_cast<const u16x8*>(
            xb + ((size_t)(ih * 256 + ip)) * 64 + ch * 32 + icg * 8);
      *reinterpret_cast<u16x8*>(&lb[(rc * 5 + icg) << 3]) = v;
    }
    __syncthreads();
    #pragma unroll
    for (int kk = 0; kk < 9; ++kk) {
      const int kh = kk / 3, kw = kk - kh * 3;
      short8 afrag[4];
      const u16* wb = wt + ((size_t)kk * 256 + oc0w + colA) * 64 + ch * 32 + g * 8;
      #pragma unroll
      for (int of = 0; of < 4; ++of)
        afrag[of] = *reinterpret_cast<const short8*>(wb + (size_t)of * 16 * 64);
      #pragma unroll
      for (int pf = 0; pf < 4; ++pf) {
        int ow = pf * 16 + colA;
        int rc = (kw == 1) ? (kh * 64 + ow) : (192 + kh * 65 + ow + (kw >> 1));
        short8 bfrag = *reinterpret_cast<const short8*>(&lb[(rc * 5 + g) << 3]);
        #pragma unroll
        for (int of = 0; of < 4; ++of)
          acc[of][pf] = __builtin_amdgcn_mfma_f32_16x16x32_bf16(
              afrag[of], bfrag, acc[of][pf], 0, 0, 0);
      }
    }
  }
  #pragma unroll
  for (int of = 0; of < 4; ++of) {
    #pragma unroll
    for (int pf = 0; pf < 4; ++pf) {
      int px = oh * 128 + ow0 + pf * 16 + colA;
      int oc = oc0w + of * 16 + g * 4;
      u16* dst = xt + ((size_t)b * HW + px) * XROW + oc;
      u16x4 pz = *reinterpret_cast<const u16x4*>(dst);
      u16x4 o;
      #pragma unroll
      for (int r = 0; r < 4; ++r)
        o[r] = f2bf(fmaxf(acc[of][pf][r], 0.f) + bf2f(pz[r]));
      *reinterpret_cast<u16x4*>(dst) = o;
    }
  }
}

// ---------------- token pipeline: proj -> gate -> l2norm (f32 out) ----------
__global__ __launch_bounds__(256) void token_kernel(
    const float* __restrict__ tok512, const float* __restrict__ proj_w,
    const float* __restrict__ proj_b, const float* __restrict__ gate_w,
    const float* __restrict__ gate_b, float* __restrict__ tok_out) {
  __shared__ float t512[512];
  __shared__ float prj[256];
  __shared__ float red[4];
  int bl = blockIdx.x;
  int c = threadIdx.x;
  const float* trow = tok512 + (size_t)bl * 512;
  t512[c] = trow[c];
  t512[c + 256] = trow[c + 256];
  __syncthreads();
  float acc = proj_b[c];
  #pragma unroll 4
  for (int k = 0; k < 512; ++k) acc = fmaf(t512[k], proj_w[k * 256 + c], acc);
  prj[c] = acc;
  __syncthreads();
  float acc2 = gate_b[c];
  #pragma unroll 4
  for (int k = 0; k < 256; ++k) acc2 = fmaf(prj[k], gate_w[k * 256 + c], acc2);
  float g = 1.f / (1.f + __expf(-acc2));
  float tv = g * acc;
  float ss = tv * tv;
  #pragma unroll
  for (int off = 1; off < 64; off <<= 1) ss += __shfl_xor(ss, off);
  if ((c & 63) == 0) red[c >> 6] = ss;
  __syncthreads();
  float tot = red[0] + red[1] + red[2] + red[3];
  tok_out[(size_t)bl * 256 + c] = tv * (1.f / fmaxf(sqrtf(tot), 1e-12f));
}

// ---------------- gvec ----------------
__global__ __launch_bounds__(256) void gvec_kernel(
    const float* __restrict__ tok, const int* __restrict__ tokens,
    float* __restrict__ gvec) {
  __shared__ float red[4];
  int b = blockIdx.x, c = threadIdx.x;
  float s = 0.f;
  for (int l = 0; l < LL; ++l) {
    if (tokens[b * LL + l] != 0) s += tok[((size_t)b * LL + l) * 256 + c];
  }
  float ss = s * s;
  #pragma unroll
  for (int off = 1; off < 64; off <<= 1) ss += __shfl_xor(ss, off);
  if ((c & 63) == 0) red[c >> 6] = ss;
  __syncthreads();
  float tot = red[0] + red[1] + red[2] + red[3];
  gvec[b * 256 + c] = s * (1.f / fmaxf(sqrtf(tot), 1e-12f));
}

// ---------------- fused attention: scores+softmax -> P in LDS -> ctx -------
__global__ __launch_bounds__(256, 1) void attn_fused(
    u16* __restrict__ xt, const float* __restrict__ tok,
    const int* __restrict__ tokens, const float* __restrict__ gvec) {
  __shared__ u16 ltok[LL * 256];   // bf16 tokens (39.4 KB)
  __shared__ u16 pl[64 * 104];     // P [px][l] (13.3 KB)
  __shared__ float lgv[256];
  __shared__ u16 lval[LL + 3];
  const int tid = threadIdx.x;
  const int b = blockIdx.y;
  const int px0 = blockIdx.x * 64;
  for (int slot = tid; slot < LL * 32; slot += 256) {
    int l = slot >> 5, cg = slot & 31;
    const float* tp = tok + ((size_t)b * LL + l) * 256 + cg * 8;
    float4 t0 = *reinterpret_cast<const float4*>(tp);
    float4 t1 = *reinterpret_cast<const float4*>(tp + 4);
    u16x8 v = {f2bf(t0.x), f2bf(t0.y), f2bf(t0.z), f2bf(t0.w),
               f2bf(t1.x), f2bf(t1.y), f2bf(t1.z), f2bf(t1.w)};
    *reinterpret_cast<u16x8*>(&ltok[l * 256 + cg * 8]) = v;
  }
  if (tid < LL) lval[tid] = (tokens[b * LL + tid] != 0) ? 1 : 0;
  lgv[tid] = gvec[b * 256 + tid];
  __syncthreads();
  const int pxl = tid >> 2;
  const int q = tid & 3;
  const int p = px0 + pxl;
  const u16* xr = xt + ((size_t)b * HW + p) * XROW;
  float s[20];
  #pragma unroll
  for (int i = 0; i < 20; ++i) s[i] = 0.f;
  float ssum = 0.f, simacc = 0.f;
  #pragma unroll 1
  for (int c0 = 0; c0 < 256; c0 += 32) {
    float x[32];
    #pragma unroll
    for (int qq = 0; qq < 4; ++qq) {
      u16x8 iv = *reinterpret_cast<const u16x8*>(xr + c0 + qq * 8);
      #pragma unroll
      for (int k = 0; k < 8; ++k) x[qq * 8 + k] = bf2f(iv[k]);
    }
    #pragma unroll
    for (int k = 0; k < 32; ++k) {
      ssum = fmaf(x[k], x[k], ssum);
      simacc = fmaf(x[k], lgv[c0 + k], simacc);
    }
    #pragma unroll
    for (int li = 0; li < 20; ++li) {
      int l = li * 4 + q;
      if (l < LL) {
        const u16* tr = &ltok[l * 256 + c0];
        float a2 = s[li];
        #pragma unroll
        for (int qq = 0; qq < 4; ++qq) {
          u16x8 tv = *reinterpret_cast<const u16x8*>(tr + qq * 8);
          #pragma unroll
          for (int k = 0; k < 8; ++k) a2 = fmaf(x[qq * 8 + k], bf2f(tv[k]), a2);
        }
        s[li] = a2;
      }
    }
  }
  const float invn = 1.f / fmaxf(sqrtf(ssum), 1e-12f);
  const float sc = invn * 0.0625f;
  float m = -1e30f;
  #pragma unroll
  for (int li = 0; li < 20; ++li) {
    int l = li * 4 + q;
    float v = (l < LL) ? (lval[l] ? s[li] * sc : -10000.f) : -1e30f;
    s[li] = v;
    m = fmaxf(m, v);
  }
  m = fmaxf(m, __shfl_xor(m, 1));
  m = fmaxf(m, __shfl_xor(m, 2));
  float sum = 0.f;
  #pragma unroll
  for (int li = 0; li < 20; ++li) {
    float e = __expf(s[li] - m);   // pad rows: exp(-1e30 - m) = 0
    s[li] = e;
    sum += e;
  }
  sum += __shfl_xor(sum, 1);
  sum += __shfl_xor(sum, 2);
  const float rs = 1.f / sum;
  #pragma unroll
  for (int li = 0; li < 20; ++li) {
    int l = li * 4 + q;
    if (l < LL) pl[pxl * 104 + l] = f2bf(s[li] * rs);
  }
  if (q == 0) {
    u16x8 sv = {f2bf(simacc * invn), 0, 0, 0, 0, 0, 0, 0};
    *reinterpret_cast<u16x8*>(xt + ((size_t)b * HW + p) * XROW + 512) = sv;
  }
  __syncthreads();
  // ---- phase 2: ctx = P @ tok, channels [q*64, q*64+64) per thread ----
  const int cbase = q * 64;
  float a[64];
  #pragma unroll
  for (int k = 0; k < 64; ++k) a[k] = 0.f;
  #pragma unroll 1
  for (int l = 0; l < LL; ++l) {
    float sl = bf2f(pl[pxl * 104 + l]);
    const u16* tr = &ltok[l * 256 + cbase];
    #pragma unroll
    for (int qq = 0; qq < 8; ++qq) {
      u16x8 tv = *reinterpret_cast<const u16x8*>(tr + qq * 8);
      #pragma unroll
      for (int k = 0; k < 8; ++k)
        a[qq * 8 + k] = fmaf(sl, bf2f(tv[k]), a[qq * 8 + k]);
    }
  }
  u16* xw = xt + ((size_t)b * HW + p) * XROW + 256 + cbase;
  #pragma unroll
  for (int qq = 0; qq < 8; ++qq) {
    u16x8 ov;
    #pragma unroll
    for (int k = 0; k < 8; ++k) ov[k] = f2bf(a[qq * 8 + k]);
    *reinterpret_cast<u16x8*>(xw + qq * 8) = ov;
  }
}

// ---------------- MFMA conv 3x3 stride-1 (R11 config + XCD swizzle) ---------
template <int CHUNKS, int XR, int OC, int OCW, bool AFFINE, bool GNST, bool RELU,
          int OROW>
__global__ __launch_bounds__(256) void convT_mfma(
    const u16* __restrict__ xt, const u16* __restrict__ wt,
    const float* __restrict__ bias, const float* __restrict__ gA,
    const float* __restrict__ gB, float* __restrict__ gnsum,
    u16* __restrict__ outT) {
  constexpr int ICPAD = CHUNKS * 32;
  constexpr int OCB = 4 * OCW;
  constexpr int NOF = OCW / 16;
  __shared__ u16 lb[7920];
  const int tid = threadIdx.x;
  const int lane = tid & 63;
  const int w = tid >> 6;
  // XCD-aware swizzle (nwg divisible by 8): each XCD owns one batch,
  // row-adjacent blocks share its L2 for the 3-row halo.
  int gx = (int)gridDim.x, gy = (int)gridDim.y;
  int lin = blockIdx.x + gx * (blockIdx.y + gy * blockIdx.z);
  int nwg = gx * gy * (int)gridDim.z;
  int swz = (lin & 7) * (nwg >> 3) + (lin >> 3);
  int bx = swz % gx;
  int rem = swz / gx;
  int by = rem % gy;
  int bz = rem / gy;
  const int oh = bx >> 1;
  const int ow0 = (bx & 1) << 6;
  const int oc0 = by * OCB + w * OCW;
  const int b = bz;
  const int colA = lane & 15;
  const int g = lane >> 4;

  f32x4 acc[NOF][4];
  #pragma unroll
  for (int of = 0; of < NOF; ++of) {
    f32x4 bv;
    #pragma unroll
    for (int r = 0; r < 4; ++r) bv[r] = bias[oc0 + of * 16 + g * 4 + r];
    #pragma unroll
    for (int pf = 0; pf < 4; ++pf) acc[of][pf] = bv;
  }

  const u16* xtb = xt + (size_t)b * HW * XR;
  for (int ch = 0; ch < CHUNKS; ++ch) {
    __syncthreads();
    #pragma unroll
    for (int it = 0; it < 4; ++it) {
      int slot = it * 256 + tid;
      if (slot < 792) {
        int icg = slot & 3;
        int rc = slot >> 2;
        int col = rc % 66;
        int row = rc / 66;
        int ih = oh + row - 1;
        int ip = ow0 - 1 + col;
        int chb = ch * 32 + icg * 8;
        u16x8 v = {0, 0, 0, 0, 0, 0, 0, 0};
        if ((unsigned)ih < 128u && (unsigned)ip < 128u && chb + 8 <= XR) {
          v = *reinterpret_cast<const u16x8*>(xtb + (size_t)(ih * 128 + ip) * XR + chb);
          if constexpr (AFFINE) {
            const float* ga = gA + b * 256 + chb;
            const float* gb2 = gB + b * 256 + chb;
            #pragma unroll
            for (int k = 0; k < 8; ++k)
              v[k] = f2bf(fmaxf(fmaf(bf2f(v[k]), ga[k], gb2[k]), 0.f));
          }
        }
        *reinterpret_cast<u16x8*>(&lb[(rc * 5 + icg) << 3]) = v;
      }
    }
    __syncthreads();
    #pragma unroll
    for (int kk = 0; kk < 9; ++kk) {
      const int kh = kk / 3, kw = kk - kh * 3;
      short8 afrag[NOF];
      const u16* wb = wt + ((size_t)kk * OC + oc0 + colA) * ICPAD + ch * 32 + g * 8;
      #pragma unroll
      for (int of = 0; of < NOF; ++of)
        afrag[of] = *reinterpret_cast<const short8*>(wb + (size_t)of * 16 * ICPAD);
      #pragma unroll
      for (int pf = 0; pf < 4; ++pf) {
        int colx = pf * 16 + colA + kw;
        short8 bfrag = *reinterpret_cast<const short8*>(
            &lb[((kh * 66 + colx) * 5 + g) << 3]);
        #pragma unroll
        for (int of = 0; of < NOF; ++of)
          acc[of][pf] = __builtin_amdgcn_mfma_f32_16x16x32_bf16(
              afrag[of], bfrag, acc[of][pf], 0, 0, 0);
      }
    }
  }
  #pragma unroll
  for (int of = 0; of < NOF; ++of) {
    float s = 0.f, ss = 0.f;
    #pragma unroll
    for (int pf = 0; pf < 4; ++pf) {
      int px = oh * 128 + ow0 + pf * 16 + colA;
      u16x4 o;
      #pragma unroll
      for (int r = 0; r < 4; ++r) {
        float v = acc[of][pf][r];
        if constexpr (RELU) v = fmaxf(v, 0.f);
        if constexpr (GNST) { s += v; ss = fmaf(v, v, ss); }
        o[r] = f2bf(v);
      }
      *reinterpret_cast<u16x4*>(
          outT + ((size_t)b * HW + px) * OROW + oc0 + of * 16 + g * 4) = o;
    }
    if constexpr (GNST) {
      #pragma unroll
      for (int off2 = 1; off2 < 16; off2 <<= 1) {
        s += __shfl_xor(s, off2);
        ss += __shfl_xor(ss, off2);
      }
      s += __shfl_xor(s, 16);
      ss += __shfl_xor(ss, 16);
      if (colA == 0 && (g & 1) == 0) {
        int grp = (oc0 + of * 16 + g * 4) >> 3;
        atomicAdd(gnsum + ((size_t)b * 32 + grp) * 2, s);
        atomicAdd(gnsum + ((size_t)b * 32 + grp) * 2 + 1, ss);
      }
    }
  }
}

// ---------------- GN finalize: sums -> per (b,c) affine a,b ----------------
__global__ __launch_bounds__(256) void gn_fin(
    const float* __restrict__ gnsum, const float* __restrict__ gg,
    const float* __restrict__ gb, float* __restrict__ gA,
    float* __restrict__ gB) {
  int b = blockIdx.x, c = threadIdx.x;
  int grp = c >> 3;
  float s = gnsum[((size_t)b * 32 + grp) * 2];
  float ss = gnsum[((size_t)b * 32 + grp) * 2 + 1];
  float m = s * (1.f / 131072.f);
  float var = ss * (1.f / 131072.f) - m * m;
  float istd = rsqrtf(var + 1e-5f);
  float a = istd * gg[c];
  gA[b * 256 + c] = a;
  gB[b * 256 + c] = gb[c] - m * a;
}

// ---------------- d3: 1x1 conv 64->1 on y2T [p][64] ----------------
__global__ __launch_bounds__(256) void d3_kernel(
    const u16* __restrict__ y2t, const float* __restrict__ w3,
    const float* __restrict__ b3, float* __restrict__ y3) {
  int idx = blockIdx.x * 256 + threadIdx.x;
  const u16* r = y2t + (size_t)idx * 64;
  float acc = b3[0];
  #pragma unroll
  for (int cg = 0; cg < 8; ++cg) {
    u16x8 v = *reinterpret_cast<const u16x8*>(r + cg * 8);
    #pragma unroll
    for (int k = 0; k < 8; ++k) acc = fmaf(bf2f(v[k]), w3[cg * 8 + k], acc);
  }
  y3[idx] = acc;
}

// ---------------- bilinear upsample 128 -> 512 ----------------
__global__ __launch_bounds__(256) void upsample_kernel(
    const float* __restrict__ y3, float* __restrict__ out) {
  int idx = blockIdx.x * 256 + threadIdx.x;
  int b = idx >> 18;
  int rem = idx & 262143;
  int Y = rem >> 9, X = rem & 511;
  float sy = (Y + 0.5f) * 0.25f - 0.5f;
  float sx = (X + 0.5f) * 0.25f - 0.5f;
  float y0f = floorf(sy), x0f = floorf(sx);
  float fy = sy - y0f, fx = sx - x0f;
  int y0 = (int)y0f, x0 = (int)x0f;
  int y0c = max(y0, 0), y1c = min(y0 + 1, 127);
  int x0c = max(x0, 0), x1c = min(x0 + 1, 127);
  const float* yb = y3 + (size_t)b * HW;
  float v00 = yb[y0c * 128 + x0c], v01 = yb[y0c * 128 + x1c];
  float v10 = yb[y1c * 128 + x0c], v11 = yb[y1c * 128 + x1c];
  out[idx] = (1.f - fy) * ((1.f - fx) * v00 + fx * v01) +
             fy * ((1.f - fx) * v10 + fx * v11);
}

extern "C" void kernel_launch(void* const* d_in, const int* in_sizes, int n_in,
                              void* d_out, int out_size, void* d_ws, size_t ws_size,
                              hipStream_t stream) {
  const float* images  = (const float*)d_in[0];
  const int*   tokens  = (const int*)d_in[1];
  const float* tok512  = (const float*)d_in[2];
  const float* conv1_w = (const float*)d_in[3];
  const float* conv1_b = (const float*)d_in[4];
  const float* conv2_w = (const float*)d_in[5];
  const float* conv2_b = (const float*)d_in[6];
  const float* sp1_w   = (const float*)d_in[7];
  const float* sp1_b   = (const float*)d_in[8];
  const float* sp2_w   = (const float*)d_in[9];
  const float* sp2_b   = (const float*)d_in[10];
  const float* proj_w  = (const float*)d_in[11];
  const float* proj_b  = (const float*)d_in[12];
  const float* gate_w  = (const float*)d_in[13];
  const float* gate_b  = (const float*)d_in[14];
  const float* d1_w    = (const float*)d_in[15];
  const float* d1_b    = (const float*)d_in[16];
  const float* gn_g    = (const float*)d_in[17];
  const float* gn_b    = (const float*)d_in[18];
  const float* d2_w    = (const float*)d_in[19];
  const float* d2_b    = (const float*)d_in[20];
  const float* d3_w    = (const float*)d_in[21];
  const float* d3_b    = (const float*)d_in[22];

  float* outp = (float*)d_out;
  if (ws_size < WS_BYTES_NEEDED) {
    float v = 10000.0f + (float)(ws_size >> 20);
    fill_kernel<<<(out_size + 255) / 256, 256, 0, stream>>>(outp, out_size, v);
    return;
  }

  char* wsb = (char*)d_ws;
  u16*   xt    = (u16*)(wsb + OFF_XT);
  u16*   x1t   = (u16*)(wsb + OFF_B);
  float* tokb  = (float*)(wsb + OFF_B);
  float* gvecb = (float*)(wsb + OFF_B + OFF_GVECB);
  u16*   y1t   = (u16*)(wsb + OFF_B);
  float* gnsum = (float*)(wsb + OFF_GNSUM);
  u16*   y2t   = (u16*)(wsb + OFF_Y2T);
  float* gA    = (float*)(wsb + OFF_GA);
  float* gB    = (float*)(wsb + OFF_GB);
  float* y3    = (float*)(wsb + OFF_Y3);

  u16* wt1  = (u16*)d_out;
  u16* wt2  = (u16*)((char*)d_out + WT1_BYTES);
  u16* wtc2 = (u16*)((char*)d_out + WT1_BYTES + WT2_BYTES);

  prep_wt<<<(9 * 256 * 544 + 255) / 256, 256, 0, stream>>>(
      d1_w, wt1, 256, 513, 544, 9 * 256 * 544);
  prep_wt<<<(9 * 64 * 256 + 255) / 256, 256, 0, stream>>>(
      d2_w, wt2, 64, 256, 256, 9 * 64 * 256);
  prep_wt<<<(9 * 256 * 64 + 255) / 256, 256, 0, stream>>>(
      conv2_w, wtc2, 256, 64, 64, 9 * 256 * 64);
  zero_gnsum<<<1, 512, 0, stream>>>(gnsum);

  pos_xt<<<256, 256, 0, stream>>>(sp1_w, sp1_b, sp2_w, sp2_b, xt);
  conv1_kernel<<<dim3(256, 8), 256, 0, stream>>>(images, conv1_w, conv1_b, x1t);
  conv2_mfma<<<dim3(256, 1, 8), 256, 0, stream>>>(x1t, wtc2, conv2_b, xt);
  token_kernel<<<BB * LL, 256, 0, stream>>>(tok512, proj_w, proj_b, gate_w,
                                            gate_b, tokb);
  gvec_kernel<<<BB, 256, 0, stream>>>(tokb, tokens, gvecb);
  attn_fused<<<dim3(256, BB), 256, 0, stream>>>(xt, tokb, tokens, gvecb);
  // d1: 513->256 MFMA (OCW=32, 64-px blocks, XCD swizzle), fused GN stats
  convT_mfma<17, XROW, 256, 32, false, true, false, 256>
      <<<dim3(256, 2, 8), 256, 0, stream>>>(xt, wt1, d1_b, nullptr, nullptr,
                                            gnsum, y1t);
  gn_fin<<<8, 256, 0, stream>>>(gnsum, gn_g, gn_b, gA, gB);
  // d2: 256->64 MFMA, GN-affine+ReLU fused at staging, ReLU out, y2T [p][64]
  convT_mfma<8, 256, 64, 16, true, false, true, 64>
      <<<dim3(256, 1, 8), 256, 0, stream>>>(y1t, wt2, d2_b, gA, gB, nullptr, y2t);
  d3_kernel<<<512, 256, 0, stream>>>(y2t, d3_w, d3_b, y3);
  upsample_kernel<<<8192, 256, 0, stream>>>(y3, outp);
}